// Round 1
// baseline (198.593 us; speedup 1.0000x reference)
//
#include <hip/hip_runtime.h>
#include <math.h>

#define VOCAB 32000
#define SEQ   2048
#define SM1   2047   // SEQ-1
#define BATCH 4

// ---------------------------------------------------------------------------
// Kernel A: one block per (b, s) row of logits. Single-pass online softmax
// (running max m, running sum s of exp(x-m)), float4 vectorized loads.
// Writes nll*mask and mask per row to workspace.
// ---------------------------------------------------------------------------
__global__ __launch_bounds__(256)
void ce_row_kernel(const float* __restrict__ y_pred,
                   const int*   __restrict__ y_true,
                   const int*   __restrict__ pad_id_p,
                   float* __restrict__ row_nll,
                   float* __restrict__ row_msk) {
    const int row = blockIdx.x;          // 0 .. BATCH*SM1-1
    const int b   = row / SM1;
    const int s   = row % SM1;
    const int tid = threadIdx.x;

    const float*  rowp  = y_pred + ((size_t)b * SEQ + s) * (size_t)VOCAB;
    const float4* rowp4 = (const float4*)rowp;

    // per-thread online max / sumexp over strided chunk
    float m    = -INFINITY;
    float ssum = 0.0f;
    for (int i = tid; i < VOCAB / 4; i += 256) {
        float4 v  = rowp4[i];
        float  m4 = fmaxf(fmaxf(v.x, v.y), fmaxf(v.z, v.w));
        if (m4 > m) {
            ssum *= __expf(m - m4);   // exp(-inf)=0 handles first iter
            m = m4;
        }
        ssum += __expf(v.x - m) + __expf(v.y - m)
              + __expf(v.z - m) + __expf(v.w - m);
    }

    // block-level (m, s) logsumexp reduction in LDS
    __shared__ float sm_m[256];
    __shared__ float sm_s[256];
    sm_m[tid] = m;
    sm_s[tid] = ssum;
    __syncthreads();
    for (int off = 128; off > 0; off >>= 1) {
        if (tid < off) {
            float m1 = sm_m[tid],       s1 = sm_s[tid];
            float m2 = sm_m[tid + off], s2 = sm_s[tid + off];
            float mm = fmaxf(m1, m2);
            sm_m[tid] = mm;
            sm_s[tid] = s1 * __expf(m1 - mm) + s2 * __expf(m2 - mm);
        }
        __syncthreads();
    }

    if (tid == 0) {
        const int tgt = y_true[b * SEQ + s + 1];   // targets = y_true[:, 1:]
        const int pad = pad_id_p[0];
        const float xt  = rowp[tgt];
        const float nll = logf(sm_s[0]) + sm_m[0] - xt;
        const float mk  = (tgt != pad) ? 1.0f : 0.0f;
        row_nll[row] = nll * mk;
        row_msk[row] = mk;
    }
}

// ---------------------------------------------------------------------------
// Kernel B: deterministic final reduction. One block: per-batch sums of
// nll and mask, per_seq = sum_nll/sum_msk, out = mean over batch.
// ---------------------------------------------------------------------------
__global__ __launch_bounds__(256)
void ce_final_kernel(const float* __restrict__ row_nll,
                     const float* __restrict__ row_msk,
                     float* __restrict__ out) {
    __shared__ float sm[256];
    const int tid = threadIdx.x;
    float acc = 0.0f;
    for (int b = 0; b < BATCH; ++b) {
        float sn = 0.0f, sc = 0.0f;
        for (int i = tid; i < SM1; i += 256) {
            sn += row_nll[b * SM1 + i];
            sc += row_msk[b * SM1 + i];
        }
        // reduce sn
        sm[tid] = sn; __syncthreads();
        for (int off = 128; off > 0; off >>= 1) {
            if (tid < off) sm[tid] += sm[tid + off];
            __syncthreads();
        }
        float tot_n = sm[0];
        __syncthreads();
        // reduce sc
        sm[tid] = sc; __syncthreads();
        for (int off = 128; off > 0; off >>= 1) {
            if (tid < off) sm[tid] += sm[tid + off];
            __syncthreads();
        }
        float tot_c = sm[0];
        __syncthreads();
        acc += tot_n / tot_c;
    }
    if (tid == 0) out[0] = acc / (float)BATCH;
}

// ---------------------------------------------------------------------------
extern "C" void kernel_launch(void* const* d_in, const int* in_sizes, int n_in,
                              void* d_out, int out_size, void* d_ws, size_t ws_size,
                              hipStream_t stream) {
    const float* y_pred = (const float*)d_in[0];
    const int*   y_true = (const int*)d_in[1];
    const int*   pad_id = (const int*)d_in[2];
    float* out = (float*)d_out;

    float* row_nll = (float*)d_ws;
    float* row_msk = row_nll + BATCH * SM1;

    ce_row_kernel<<<BATCH * SM1, 256, 0, stream>>>(y_pred, y_true, pad_id,
                                                   row_nll, row_msk);
    ce_final_kernel<<<1, 256, 0, stream>>>(row_nll, row_msk, out);
}

// Round 3
// 170.425 us; speedup vs baseline: 1.1653x; 1.1653x over previous
//
#include <hip/hip_runtime.h>
#include <math.h>

#define VOCAB 32000
#define SEQ   2048
#define SM1   2047   // SEQ-1
#define BATCH 4
#define NTHR  320    // 5 waves; 8000 float4 / 320 = exactly 25 per thread

typedef float floatx4 __attribute__((ext_vector_type(4)));

// ---------------------------------------------------------------------------
// Kernel A: one block per (b, s) row. Single-pass online softmax with
// nontemporal float4 loads, 4 independent partial sums, shfl-based reduce.
// ---------------------------------------------------------------------------
__global__ __launch_bounds__(NTHR)
void ce_row_kernel(const float* __restrict__ y_pred,
                   const int*   __restrict__ y_true,
                   const int*   __restrict__ pad_id_p,
                   float* __restrict__ row_nll,
                   float* __restrict__ row_msk) {
    const int row = blockIdx.x;          // 0 .. BATCH*SM1-1
    const int b   = row / SM1;
    const int s   = row % SM1;
    const int tid = threadIdx.x;

    const float*   rowp  = y_pred + ((size_t)b * SEQ + s) * (size_t)VOCAB;
    const floatx4* rowp4 = (const floatx4*)rowp;

    float m  = -INFINITY;
    float p0 = 0.0f, p1 = 0.0f, p2 = 0.0f, p3 = 0.0f;

#pragma unroll 5
    for (int it = 0; it < 25; ++it) {
        const int i = tid + it * NTHR;
        floatx4 v = __builtin_nontemporal_load(&rowp4[i]);
        float m4 = fmaxf(fmaxf(v.x, v.y), fmaxf(v.z, v.w));
        if (m4 > m) {
            const float r = __expf(m - m4);   // exp(-inf)=0 on first iter
            p0 *= r; p1 *= r; p2 *= r; p3 *= r;
            m = m4;
        }
        p0 += __expf(v.x - m);
        p1 += __expf(v.y - m);
        p2 += __expf(v.z - m);
        p3 += __expf(v.w - m);
    }
    float ssum = (p0 + p1) + (p2 + p3);

    // wave-level (m, s) logsumexp butterfly
    for (int off = 32; off > 0; off >>= 1) {
        const float m2 = __shfl_xor(m, off);
        const float s2 = __shfl_xor(ssum, off);
        const float mm = fmaxf(m, m2);
        ssum = ssum * __expf(m - mm) + s2 * __expf(m2 - mm);
        m = mm;
    }

    // merge 5 wave results
    __shared__ float sm_m[NTHR / 64];
    __shared__ float sm_s[NTHR / 64];
    const int wid = tid >> 6;
    if ((tid & 63) == 0) { sm_m[wid] = m; sm_s[wid] = ssum; }
    __syncthreads();

    if (tid == 0) {
        float M = sm_m[0], S = sm_s[0];
#pragma unroll
        for (int w = 1; w < NTHR / 64; ++w) {
            const float m2 = sm_m[w], s2 = sm_s[w];
            const float mm = fmaxf(M, m2);
            S = S * __expf(M - mm) + s2 * __expf(m2 - mm);
            M = mm;
        }
        const int tgt = y_true[b * SEQ + s + 1];   // targets = y_true[:, 1:]
        const int pad = pad_id_p[0];
        const float xt  = rowp[tgt];
        const float nll = logf(S) + M - xt;
        const float mk  = (tgt != pad) ? 1.0f : 0.0f;
        row_nll[row] = nll * mk;
        row_msk[row] = mk;
    }
}

// ---------------------------------------------------------------------------
// Kernel B: deterministic final reduction. One block.
// ---------------------------------------------------------------------------
__global__ __launch_bounds__(256)
void ce_final_kernel(const float* __restrict__ row_nll,
                     const float* __restrict__ row_msk,
                     float* __restrict__ out) {
    __shared__ float sm[256];
    const int tid = threadIdx.x;
    float acc = 0.0f;
    for (int b = 0; b < BATCH; ++b) {
        float sn = 0.0f, sc = 0.0f;
        for (int i = tid; i < SM1; i += 256) {
            sn += row_nll[b * SM1 + i];
            sc += row_msk[b * SM1 + i];
        }
        sm[tid] = sn; __syncthreads();
        for (int off = 128; off > 0; off >>= 1) {
            if (tid < off) sm[tid] += sm[tid + off];
            __syncthreads();
        }
        const float tot_n = sm[0];
        __syncthreads();
        sm[tid] = sc; __syncthreads();
        for (int off = 128; off > 0; off >>= 1) {
            if (tid < off) sm[tid] += sm[tid + off];
            __syncthreads();
        }
        const float tot_c = sm[0];
        __syncthreads();
        acc += tot_n / tot_c;
    }
    if (tid == 0) out[0] = acc / (float)BATCH;
}

// ---------------------------------------------------------------------------
extern "C" void kernel_launch(void* const* d_in, const int* in_sizes, int n_in,
                              void* d_out, int out_size, void* d_ws, size_t ws_size,
                              hipStream_t stream) {
    const float* y_pred = (const float*)d_in[0];
    const int*   y_true = (const int*)d_in[1];
    const int*   pad_id = (const int*)d_in[2];
    float* out = (float*)d_out;

    float* row_nll = (float*)d_ws;
    float* row_msk = row_nll + BATCH * SM1;

    ce_row_kernel<<<BATCH * SM1, NTHR, 0, stream>>>(y_pred, y_true, pad_id,
                                                    row_nll, row_msk);
    ce_final_kernel<<<1, 256, 0, stream>>>(row_nll, row_msk, out);
}